// Round 4
// baseline (72.016 us; speedup 1.0000x reference)
//
#include <hip/hip_runtime.h>

// RandomShift (DrQ-style): x[512,9,84,84] f32, shift[512,2] int32 in [0,8].
// out[n,c,i,j] = bilinear tap of zero-padded x at (row t = j*91/83+s1-4ish,
// col u = i*91/83+s0-4ish); taps valid only for image coords in [0,84).
//
// v3: 2 blocks per plane (j-halves) -> 17.8KB LDS -> 8 blocks/CU x 4 waves
// = 32 waves/CU (full occupancy). Staging via global_load_lds (16B/lane,
// linear row-major LDS). 4 taps read as {b, b+1, b+84, b+85} -> 2x
// ds_read2_b32. Boundary handled by clamped-base slot weights:
//   cb = clamp(t0, lo, hi); slot0 = cb, slot1 = cb+1
//   ws0 = (t0==cb)?w0 : (t0+1==cb)?w1 : 0
//   ws1 = (t0==cb)?w1 : (t0-1==cb)?w0 : 0
// (covers interior / t0 = lo-1 / t0 = hi+1 / fully-OOB cases exactly.)

constexpr int HW   = 84;
constexpr int NPLANE = HW * HW;
constexpr int NR0  = 53;            // half 0 stages rows [0,53)
constexpr int NR1  = 40;            // half 1 stages rows [44,84)
constexpr int LDSD = NR0 * HW;      // 4452 dwords = 17808 B

typedef float vfloat4 __attribute__((ext_vector_type(4)));

__device__ __forceinline__ int iclamp(int v, int lo, int hi) {
    return v < lo ? lo : (v > hi ? hi : v);
}

__global__ __launch_bounds__(256) void rshift_kernel(
    const float* __restrict__ x,
    const int*   __restrict__ shift,
    float*       __restrict__ out)
{
    __shared__ float lds[LDSD];

    const int bid   = blockIdx.x;
    const int half  = bid & 1;
    const int plane = bid >> 1;           // n*9 + c
    const int n     = plane / 9;
    const float s0  = (float)shift[2 * n];
    const float s1  = (float)shift[2 * n + 1];
    const float R   = 91.0f / 83.0f;
    const int t     = threadIdx.x;

    const int rb = half ? 44 : 0;         // first staged row
    const int NR = half ? NR1 : NR0;      // staged row count
    const int NQ = half ? 10 : 11;        // j-quads this half
    const int j0 = half ? 44 : 0;         // first output j

    const float* __restrict__ src = x   + (size_t)plane * NPLANE + rb * HW;
    float*       __restrict__ dst = out + (size_t)plane * NPLANE;

    // ---- stage NR*84 dwords via global_load_lds, 16B per lane ----
    const int quads  = NR * (HW / 4);     // float4 count (NR*84 % 4 == 0)
    const int wv     = t >> 6;
    const int rounds = (quads + 255) >> 8;
    for (int r = 0; r < rounds; ++r) {
        int lq = t + (r << 8);
        if (lq < quads) {
            const float* g = src + lq * 4;
            __builtin_amdgcn_global_load_lds(
                (const __attribute__((address_space(1))) float*)g,
                (__attribute__((address_space(3))) float*)&lds[(r << 10) + (wv << 8)],
                16, 0, 0);
        }
    }

    // ---- per-thread y-params (jq fixed per thread -> hoisted) ----
    const int jq    = t % NQ;
    const int ibase = t / NQ;
    float wy0s[4], wy1s[4];
    int   boff[4];
    #pragma unroll
    for (int e = 0; e < 4; ++e) {
        int   j  = j0 + 4 * jq + e;
        float fy = fmaf((float)j, R, s1);
        int   y0 = (int)fy;               // fy >= 0
        float w1 = fy - (float)y0;
        float w0 = 1.0f - w1;
        int   t0 = y0 - 4;                // image-space row of first tap
        int   cb = iclamp(t0, rb, rb + NR - 2);
        wy0s[e] = (t0 == cb) ? w0 : ((t0 + 1 == cb) ? w1 : 0.0f);
        wy1s[e] = (t0 == cb) ? w1 : ((t0 - 1 == cb) ? w0 : 0.0f);
        boff[e] = (cb - rb) * HW;
    }

    __syncthreads();                      // drains vmcnt for global_load_lds

    // ---- compute: k in [0,4), i = ibase + k*ISTEP (dup i's benign) ----
    const int ISTEP = half ? 25 : 23;
    #pragma unroll
    for (int k = 0; k < 4; ++k) {
        int i = ibase + k * ISTEP;
        if (i < HW) {
            float fx = fmaf((float)i, R, s0);
            int   x0 = (int)fx;
            float w1 = fx - (float)x0;
            float w0 = 1.0f - w1;
            int   u0 = x0 - 4;            // image-space col of first tap
            int   cb = iclamp(u0, 0, HW - 2);
            float wx0 = (u0 == cb) ? w0 : ((u0 + 1 == cb) ? w1 : 0.0f);
            float wx1 = (u0 == cb) ? w1 : ((u0 - 1 == cb) ? w0 : 0.0f);

            vfloat4 o;
            #pragma unroll
            for (int e = 0; e < 4; ++e) {
                int   b   = boff[e] + cb;
                float v00 = lds[b];
                float v10 = lds[b + 1];
                float v01 = lds[b + HW];
                float v11 = lds[b + HW + 1];
                o[e] = wy0s[e] * fmaf(wx0, v00, wx1 * v10)
                     + wy1s[e] * fmaf(wx0, v01, wx1 * v11);
            }
            __builtin_nontemporal_store(
                o, reinterpret_cast<vfloat4*>(dst + (size_t)i * HW + j0 + 4 * jq));
        }
    }
}

extern "C" void kernel_launch(void* const* d_in, const int* in_sizes, int n_in,
                              void* d_out, int out_size, void* d_ws, size_t ws_size,
                              hipStream_t stream) {
    const float* x     = (const float*)d_in[0];
    const int*   shift = (const int*)d_in[1];
    float*       out   = (float*)d_out;
    const int blocks = 512 * 9 * 2;       // 2 j-halves per (n,c) plane
    rshift_kernel<<<blocks, 256, 0, stream>>>(x, shift, out);
}

// Round 5
// 45.210 us; speedup vs baseline: 1.5929x; 1.5929x over previous
//
#include <hip/hip_runtime.h>

// RandomShift (DrQ-style): x[512,9,84,84] f32, shift[512,2] int32 in [0,8].
// out[n,c,i,j] = bilinear tap of zero-padded x at
// (row = j*91/83 + s1 - 4, col = i*91/83 + s0 - 4) in image coords;
// taps valid only for coords in [0,84).
//
// v4 = R2 structure (one block/plane, transposed LDS stride 85, hoisted
// y-params, lane = jq + 21*isub) + two upgrades:
//  (a) slot-weight boundary trick: taps always read adjacent pair [cb,cb+1]
//      -> ds_read2_b32 merge, halving LDS read instructions:
//        cb = clamp(t0, 0, 82); ws0 = (t0==cb)?w0 : (t0+1==cb)?w1 : 0
//                               ws1 = (t0==cb)?w1 : (t0-1==cb)?w0 : 0
//      (covers interior / t0=-1 / t0=83 / fully-OOB exactly.)
//  (b) 512 threads/block: 8 waves x 4 blocks/CU = 32 waves/CU (100% occ).

constexpr int HW     = 84;
constexpr int LDSW   = 85;           // gcd(85,32)=1 -> conflict-free staging
constexpr int NPLANE = HW * HW;      // 7056

typedef float vfloat4 __attribute__((ext_vector_type(4)));

__device__ __forceinline__ int iclamp(int v, int lo, int hi) {
    return v < lo ? lo : (v > hi ? hi : v);
}

__global__ __launch_bounds__(512) void rshift_kernel(
    const float* __restrict__ x,
    const int*   __restrict__ shift,
    float*       __restrict__ out)
{
    __shared__ float lds[HW * LDSW];         // lds[col*LDSW + row] (transposed)

    const int plane = blockIdx.x;            // n*9 + c
    const int n     = plane / 9;
    const float s0  = (float)shift[2 * n];       // along i (columns)
    const float s1  = (float)shift[2 * n + 1];   // along j (rows)
    const float* __restrict__ src = x   + (size_t)plane * NPLANE;
    float*       __restrict__ dst = out + (size_t)plane * NPLANE;
    const int t = threadIdx.x;
    const float R = 91.0f / 83.0f;

    const int lane = t & 63;
    const int wv   = t >> 6;             // 0..7
    const int jq   = lane % 21;          // j-quad within row
    const int isub = lane / 21;          // 0..2 active, 3 -> idle lane

    // ---- per-thread y-params (loop-invariant), slot-weight form ----
    float wy0s[4], wy1s[4];
    int   rbase[4];
    #pragma unroll
    for (int e = 0; e < 4; ++e) {
        float fy = fmaf((float)(4 * jq + e), R, s1);
        int   y0 = (int)fy;              // fy >= 0
        float w1 = fy - (float)y0;
        float w0 = 1.0f - w1;
        int   t0 = y0 - 4;               // image-space row of first tap
        int   cb = iclamp(t0, 0, HW - 2);
        wy0s[e] = (t0 == cb) ? w0 : ((t0 + 1 == cb) ? w1 : 0.0f);
        wy1s[e] = (t0 == cb) ? w1 : ((t0 - 1 == cb) ? w0 : 0.0f);
        rbase[e] = cb;
    }

    // ---- stage plane into LDS, transposed ----
    // consecutive lanes: consecutive cols -> write bank stride 21,
    // gcd(21,32)=1 -> conflict-free; global reads fully coalesced.
    #pragma unroll
    for (int k = 0; k < 14; ++k) {
        int idx = t + k * 512;
        if (idx < NPLANE) {
            int row = idx / HW;
            int col = idx - row * HW;
            lds[col * LDSW + row] = src[idx];
        }
    }
    __syncthreads();

    // ---- compute: 4 sweeps x (3 i-rows per wave), float4 store ----
    if (isub < 3) {
        #pragma unroll
        for (int k = 0; k < 4; ++k) {
            int i = k * 24 + wv * 3 + isub;     // each i in [0,84) exactly once
            if (i < HW) {
                float fx = fmaf((float)i, R, s0);
                int   x0 = (int)fx;
                float w1 = fx - (float)x0;
                float w0 = 1.0f - w1;
                int   u0 = x0 - 4;              // image-space col of first tap
                int   cb = iclamp(u0, 0, HW - 2);
                float wx0 = (u0 == cb) ? w0 : ((u0 + 1 == cb) ? w1 : 0.0f);
                float wx1 = (u0 == cb) ? w1 : ((u0 - 1 == cb) ? w0 : 0.0f);
                int   cu0 = cb * LDSW;
                int   cu1 = cu0 + LDSW;

                vfloat4 o;
                #pragma unroll
                for (int e = 0; e < 4; ++e) {
                    int   b0  = cu0 + rbase[e];
                    int   b1  = cu1 + rbase[e];
                    float v00 = lds[b0];        // pair (b0, b0+1): ds_read2_b32
                    float v01 = lds[b0 + 1];
                    float v10 = lds[b1];        // pair (b1, b1+1): ds_read2_b32
                    float v11 = lds[b1 + 1];
                    o[e] = wx0 * fmaf(wy0s[e], v00, wy1s[e] * v01)
                         + wx1 * fmaf(wy0s[e], v10, wy1s[e] * v11);
                }
                __builtin_nontemporal_store(
                    o, reinterpret_cast<vfloat4*>(dst + (size_t)i * HW + 4 * jq));
            }
        }
    }
}

extern "C" void kernel_launch(void* const* d_in, const int* in_sizes, int n_in,
                              void* d_out, int out_size, void* d_ws, size_t ws_size,
                              hipStream_t stream) {
    const float* x     = (const float*)d_in[0];
    const int*   shift = (const int*)d_in[1];
    float*       out   = (float*)d_out;
    const int planes = 512 * 9;   // N*C, one block per plane
    rshift_kernel<<<planes, 512, 0, stream>>>(x, shift, out);
}